// Round 8
// baseline (65.555 us; speedup 1.0000x reference)
//
#include <hip/hip_runtime.h>
#include <cstdint>

#define NTOPK 13
#define FEPS 1e-9f
#define SLOTS 4         // per-(gt, anchor-tile) key slots (positives/tile ~<=1)
#define KMAX 8          // max key slots per lane in select (supports NT*SLOTS<=512)
#define MASKED_FLAG (1 << 30)
#define SENTINEL 0xFFFFFFFFFFFFFFFFull

// ---------------------------------------------------------------------------
// metric[l] for one gt. Identical arithmetic to the reference.
// ---------------------------------------------------------------------------
__device__ __forceinline__ float tal_metric(int l, float4 gb, float ag,
                                            const float4* __restrict__ pb,
                                            const float* __restrict__ ps,
                                            const float2* __restrict__ apt,
                                            int C) {
    float2 a = apt[l];
    float dmin = fminf(fminf(a.x - gb.x, a.y - gb.y),
                       fminf(gb.z - a.x, gb.w - a.y));
    float m = 0.0f;
    if (dmin > FEPS) {
        float4 p = pb[l];
        float iw = fmaxf(fminf(gb.z, p.z) - fmaxf(gb.x, p.x), 0.0f);
        float ih = fmaxf(fminf(gb.w, p.w) - fmaxf(gb.y, p.y), 0.0f);
        float inter = iw * ih;
        float ap2 = (p.z - p.x) * (p.w - p.y);
        float iou = inter / (((ag + ap2) - inter) + 1e-9f);
        m = ps[(size_t)l * C] * powf(iou, 6.0f);
    }
    return m;
}

// ---------------------------------------------------------------------------
// Kernel 1: scan. Block = (anchor tile, batch). Thread owns one anchor and
// loops all n gts staged in LDS.
//  - IoU computed per pair; division SKIPPED when inter==0 (iou==0 exactly).
//  - per-anchor argmax-IoU packed key (iou_bits<<32 | ~g) -> plain store.
//  - positives (metric>0) allocated into this block's EXCLUSIVE key range
//    keys[bg][tile][0..SLOTS) via LDS counters; unused slots zero-filled,
//    overflow marked with SENTINEL (select falls back to dense recompute).
//  - block also zeroes its cc rows; tile==0 blocks zero max_m/max_i.
// No global pre-zeroing needed anywhere.
// ---------------------------------------------------------------------------
__global__ __launch_bounds__(256) void k_scan(
        const float* __restrict__ pred_scores,
        const float4* __restrict__ pred_bboxes,
        const float2* __restrict__ anchor_points,
        const int* __restrict__ gt_labels,
        const float4* __restrict__ gt_bboxes,
        const float* __restrict__ pad_gt_mask,
        unsigned long long* __restrict__ keys,       // [B*n][NT][SLOTS]
        unsigned long long* __restrict__ cc,         // [B*L] pick-count|g-sum
        unsigned long long* __restrict__ iou_part,   // [B*L]
        uint32_t* __restrict__ max_m,
        uint32_t* __restrict__ max_i,
        int B, int L, int C, int n, int NT) {
    int b = blockIdx.y;
    int tile = blockIdx.x;
    int l0 = tile * 256;
    int t = threadIdx.x;

    extern __shared__ char smem[];
    float4* sbox = (float4*)smem;          // RAW gt boxes (argmax uses unmasked)
    int*    slab = (int*)(sbox + n);       // label | MASKED_FLAG
    int*    scnt = slab + n;               // per-gt slot counters

    for (int i = t; i < n; i += 256) {
        sbox[i] = gt_bboxes[(size_t)b * n + i];
        int lm = gt_labels[(size_t)b * n + i];
        if (pad_gt_mask[(size_t)b * n + i] == 0.0f) lm |= MASKED_FLAG;
        slab[i] = lm;
        scnt[i] = 0;
    }
    {   // zero this block's cc rows (consumed by k_select, which runs later)
        int rows = min(256, L - l0);
        for (int r = t; r < rows; r += 256) cc[(size_t)b * L + l0 + r] = 0ull;
        if (tile == 0)  // zero per-gt maxima for this batch
            for (int i = t; i < 2 * n; i += 256)
                (i < n ? max_m : max_i)[(size_t)b * n + (i < n ? i : i - n)] = 0u;
    }
    __syncthreads();

    int l = l0 + t;
    if (l < L) {
        float2 a = anchor_points[l];
        float4 p = pred_bboxes[(size_t)b * L + l];
        float ap = (p.z - p.x) * (p.w - p.y);
        const float* ps = pred_scores + ((size_t)b * L + l) * C;

        unsigned long long bestkey = 0ull;
        for (int i = 0; i < n; ++i) {
            float4 gb = sbox[i];
            float iw = fmaxf(fminf(gb.z, p.z) - fmaxf(gb.x, p.x), 0.0f);
            float ih = fmaxf(fminf(gb.w, p.w) - fmaxf(gb.y, p.y), 0.0f);
            float inter = iw * ih;
            unsigned long long akey = (unsigned long long)(uint32_t)(~i);
            int lm = slab[i];
            if (inter > 0.0f) {
                float ag = (gb.z - gb.x) * (gb.w - gb.y);
                float iou = inter / (((ag + ap) - inter) + 1e-9f);
                akey |= (unsigned long long)__float_as_uint(iou) << 32;
                if (!(lm & MASKED_FLAG)) {
                    float dmin = fminf(fminf(a.x - gb.x, a.y - gb.y),
                                       fminf(gb.z - a.x, gb.w - a.y));
                    if (dmin > FEPS) {
                        float m = ps[lm] * powf(iou, 6.0f);
                        if (m > 0.0f) {
                            int slot = atomicAdd(&scnt[i], 1);
                            if (slot < SLOTS)
                                keys[(((size_t)(b * n + i)) * NT + tile) * SLOTS + slot] =
                                    ((unsigned long long)__float_as_uint(m) << 32) |
                                    (uint32_t)(~l);
                        }
                    }
                }
            }
            if (akey > bestkey) bestkey = akey;   // iou desc, then lowest g
        }
        iou_part[(size_t)b * L + l] = bestkey;
    }
    __syncthreads();

    // zero unused slots / mark overflow in this block's exclusive key range
    for (int s = t; s < n * SLOTS; s += 256) {
        int g = s / SLOTS, j = s - g * SLOTS;
        int c = scnt[g];
        unsigned long long* dst =
            &keys[(((size_t)(b * n + g)) * NT + tile) * SLOTS + j];
        if (c > SLOTS && j == 0) *dst = SENTINEL;
        else if (j >= c) *dst = 0ull;
    }
}

// ---------------------------------------------------------------------------
// Kernel 2: selection. One wave per (b,g):
//  - load the bg's NT*SLOTS keys (2-3 per lane), 13 shfl-max rounds
//    (key desc == value desc then index asc; 0-key = empty sorts last),
//    uniform early break when exhausted; ballot zero-fill of lowest-index
//    zero-metric anchors; SENTINEL or oversize -> dense recompute fallback.
//  - picks: atomicAdd cc[b,l] += (1<<32)|(g+1) iff anchor in-gts.
// ---------------------------------------------------------------------------
__global__ __launch_bounds__(256) void k_select(
        const float* __restrict__ pred_scores,
        const float4* __restrict__ pred_bboxes,
        const float2* __restrict__ anchor_points,
        const int* __restrict__ gt_labels,
        const float4* __restrict__ gt_bboxes,
        const float* __restrict__ pad_gt_mask,
        const unsigned long long* __restrict__ keys,
        unsigned long long* __restrict__ cc,
        int B, int L, int C, int n, int NT) {
    int wid = threadIdx.x >> 6;
    int lane = threadIdx.x & 63;
    int bg = blockIdx.x * 4 + wid;
    if (bg >= B * n) return;
    if (pad_gt_mask[bg] == 0.0f) return;
    int b = bg / n;
    int g = bg - b * n;

    int TK = NT * SLOTS;
    int mypick = -1;
    bool dense = (TK > 64 * KMAX);

    if (!dense) {
        unsigned long long lk[KMAX];
        int nk = 0;
        bool sent = false;
        for (int s = lane; s < TK; s += 64) {
            unsigned long long k = keys[(size_t)bg * TK + s];
            if (k == SENTINEL) sent = true;
            lk[nk++] = k;
        }
        for (int j = nk; j < KMAX; ++j) lk[j] = 0ull;
        dense = (__ballot(sent) != 0ull);

        if (!dense) {
            int np = 0;
            for (int k = 0; k < NTOPK; ++k) {
                unsigned long long mk = 0ull;
                #pragma unroll
                for (int j = 0; j < KMAX; ++j) mk = (lk[j] > mk) ? lk[j] : mk;
                for (int s = 1; s < 64; s <<= 1) {
                    unsigned long long o = __shfl_xor(mk, s);
                    if (o > mk) mk = o;
                }
                if (mk == 0ull) break;      // uniform across wave
                #pragma unroll
                for (int j = 0; j < KMAX; ++j) if (lk[j] == mk) lk[j] = 0ull;
                if (lane == k) mypick = (int)~(uint32_t)mk;
                ++np;
            }
            // zero-fill: lowest-index anchors not among the positive picks
            int fill = np, c = 0;
            while (fill < NTOPK) {
                bool inP = __ballot(lane < np && mypick == c) != 0ull;
                if (!inP) {
                    if (lane == fill) mypick = c;
                    ++fill;
                }
                ++c;
            }
        }
    }

    if (dense) {
        // dense recompute fallback (not taken for this data)
        float4 gb = gt_bboxes[bg];
        float ag = (gb.z - gb.x) * (gb.w - gb.y);
        const float4* pb = pred_bboxes + (size_t)b * L;
        const float*  ps = pred_scores + ((size_t)b * L) * C + gt_labels[bg];
        for (int k = 0; k < NTOPK; ++k) {
            unsigned long long bk = 0ull;
            for (int l = lane; l < L; l += 64) {
                bool taken = false;
                for (int j = 0; j < k; ++j)
                    taken |= (__shfl(mypick, j) == l);
                if (taken) continue;
                float m = tal_metric(l, gb, ag, pb, ps, anchor_points, C);
                unsigned long long key =
                    ((unsigned long long)__float_as_uint(m) << 32) | (uint32_t)(~l);
                if (key > bk) bk = key;
            }
            for (int s = 1; s < 64; s <<= 1) {
                unsigned long long o = __shfl_xor(bk, s);
                if (o > bk) bk = o;
            }
            if (lane == k) mypick = (int)~(uint32_t)bk;
        }
    }

    if (lane < NTOPK && mypick >= 0) {
        int l = mypick;
        float4 gb = gt_bboxes[bg];
        float2 a = anchor_points[l];
        float dmin = fminf(fminf(a.x - gb.x, a.y - gb.y),
                           fminf(gb.z - a.x, gb.w - a.y));
        if (dmin > FEPS) {
            atomicAdd(&cc[(size_t)b * L + l],
                      (1ull << 32) | (unsigned long long)(uint32_t)(g + 1));
        }
    }
}

// ---------------------------------------------------------------------------
// Kernel 3: per (b,l): resolve assignment from the cc word; sum>1 uses the
// precomputed argmax-IoU. Pure streaming.
// ---------------------------------------------------------------------------
__global__ __launch_bounds__(256) void k_assign(
        const float* __restrict__ pred_scores,
        const float4* __restrict__ pred_bboxes,
        const float4* __restrict__ gt_bboxes,
        const int* __restrict__ gt_labels,
        const unsigned long long* __restrict__ cc,
        const unsigned long long* __restrict__ iou_part,
        const int* __restrict__ bg_ptr,
        int* __restrict__ assigned_g,
        float* __restrict__ align_val,
        uint32_t* __restrict__ max_m,
        uint32_t* __restrict__ max_i,
        float* __restrict__ out_labels,
        float4* __restrict__ out_bboxes,
        int B, int L, int C, int n) {
    int idx = blockIdx.x * blockDim.x + threadIdx.x;
    if (idx >= B * L) return;
    int b = idx / L;

    unsigned long long w = cc[idx];
    int count = (int)(w >> 32);
    int g;
    if (count == 0) g = -1;
    else if (count == 1) g = (int)(uint32_t)w - 1;
    else g = (int)~(uint32_t)iou_part[idx];   // first-max argmax-IoU over gts
    assigned_g[idx] = g;

    float av = 0.0f;
    if (g >= 0) {
        float4 p = pred_bboxes[idx];
        float ap = (p.z - p.x) * (p.w - p.y);
        float4 gb = gt_bboxes[(size_t)b * n + g];
        float iw = fmaxf(fminf(gb.z, p.z) - fmaxf(gb.x, p.x), 0.0f);
        float ih = fmaxf(fminf(gb.w, p.w) - fmaxf(gb.y, p.y), 0.0f);
        float inter = iw * ih;
        float ag = (gb.z - gb.x) * (gb.w - gb.y);
        float iou = inter / (((ag + ap) - inter) + 1e-9f);
        int label = gt_labels[(size_t)b * n + g];
        float score = pred_scores[(size_t)idx * C + label];
        av = score * powf(iou, 6.0f);
        atomicMax(&max_m[(size_t)b * n + g], __float_as_uint(av));
        atomicMax(&max_i[(size_t)b * n + g], __float_as_uint(iou));
        out_labels[idx] = (float)label;
        out_bboxes[idx] = gb;
    } else {
        out_labels[idx] = (float)(*bg_ptr);
        out_bboxes[idx] = gt_bboxes[(size_t)b * n];  // agi==0 gather, unmasked
    }
    align_val[idx] = av;
}

// ---------------------------------------------------------------------------
// Kernel 4: scores, float4-vectorized (C % 4 == 0 path).
// ---------------------------------------------------------------------------
__global__ __launch_bounds__(256) void k_scores4(
        const int* __restrict__ assigned_g,
        const float* __restrict__ align_val,
        const uint32_t* __restrict__ max_m,
        const uint32_t* __restrict__ max_i,
        const int* __restrict__ gt_labels,
        const int* __restrict__ bg_ptr,
        float4* __restrict__ out_scores,
        int B, int L, int C, int n, int total4) {
    int idx = blockIdx.x * blockDim.x + threadIdx.x;
    if (idx >= total4) return;
    int C4 = C >> 2;
    int c0 = (idx % C4) * 4;
    int bl = idx / C4;
    int g = assigned_g[bl];
    float4 v = make_float4(0.f, 0.f, 0.f, 0.f);
    if (g >= 0) {
        int b = bl / L;
        int label = gt_labels[(size_t)b * n + g];
        int bgi = *bg_ptr;
        float mm = __uint_as_float(max_m[(size_t)b * n + g]);
        float mi = __uint_as_float(max_i[(size_t)b * n + g]);
        float val = align_val[bl] / (mm + FEPS) * mi;
        int cls0 = (c0     < bgi) ? c0     : c0 + 1;
        int cls1 = (c0 + 1 < bgi) ? c0 + 1 : c0 + 2;
        int cls2 = (c0 + 2 < bgi) ? c0 + 2 : c0 + 3;
        int cls3 = (c0 + 3 < bgi) ? c0 + 3 : c0 + 4;
        if (cls0 == label) v.x = val;
        if (cls1 == label) v.y = val;
        if (cls2 == label) v.z = val;
        if (cls3 == label) v.w = val;
    }
    out_scores[idx] = v;
}

__global__ __launch_bounds__(256) void k_scores1(
        const int* __restrict__ assigned_g,
        const float* __restrict__ align_val,
        const uint32_t* __restrict__ max_m,
        const uint32_t* __restrict__ max_i,
        const int* __restrict__ gt_labels,
        const int* __restrict__ bg_ptr,
        float* __restrict__ out_scores,
        int B, int L, int C, int n, int total) {
    int idx = blockIdx.x * blockDim.x + threadIdx.x;
    if (idx >= total) return;
    int c = idx % C;
    int bl = idx / C;
    int g = assigned_g[bl];
    float v = 0.0f;
    if (g >= 0) {
        int b = bl / L;
        int label = gt_labels[(size_t)b * n + g];
        int bgi = *bg_ptr;
        int cls = (c < bgi) ? c : c + 1;
        if (cls == label) {
            float mm = __uint_as_float(max_m[(size_t)b * n + g]);
            float mi = __uint_as_float(max_i[(size_t)b * n + g]);
            v = align_val[bl] / (mm + FEPS) * mi;
        }
    }
    out_scores[idx] = v;
}

// ---------------------------------------------------------------------------
extern "C" void kernel_launch(void* const* d_in, const int* in_sizes, int n_in,
                              void* d_out, int out_size, void* d_ws, size_t ws_size,
                              hipStream_t stream) {
    const float*  pred_scores   = (const float*)d_in[0];
    const float4* pred_bboxes   = (const float4*)d_in[1];
    const float2* anchor_points = (const float2*)d_in[2];
    const int*    gt_labels     = (const int*)d_in[3];
    const float4* gt_bboxes     = (const float4*)d_in[4];
    const float*  pad_gt_mask   = (const float*)d_in[5];
    const int*    bg_ptr        = (const int*)d_in[6];

    const int L = in_sizes[2] / 2;
    const int B = in_sizes[1] / (L * 4);
    const int C = in_sizes[0] / (B * L);
    const int n = in_sizes[3] / B;
    const int NT = (L + 255) / 256;

    char* ws = (char*)d_ws;
    unsigned long long* keys = (unsigned long long*)ws;
    ws += (size_t)B * n * NT * SLOTS * sizeof(unsigned long long);
    unsigned long long* cc = (unsigned long long*)ws;
    ws += (size_t)B * L * sizeof(unsigned long long);
    unsigned long long* iou_part = (unsigned long long*)ws;
    ws += (size_t)B * L * sizeof(unsigned long long);
    uint32_t* max_m    = (uint32_t*)ws;  ws += (size_t)B * n * sizeof(uint32_t);
    uint32_t* max_i    = (uint32_t*)ws;  ws += (size_t)B * n * sizeof(uint32_t);
    int*      assigned_g = (int*)ws;     ws += (size_t)B * L * sizeof(int);
    float*    align_val  = (float*)ws;   ws += (size_t)B * L * sizeof(float);

    float*  out_labels = (float*)d_out;
    float4* out_bboxes = (float4*)((float*)d_out + (size_t)B * L);
    float*  out_scores = (float*)d_out + (size_t)B * L * 5;

    {
        dim3 grid(NT, B);
        size_t smem = (size_t)n * (sizeof(float4) + 2 * sizeof(int));
        k_scan<<<grid, 256, smem, stream>>>(
            pred_scores, pred_bboxes, anchor_points, gt_labels, gt_bboxes,
            pad_gt_mask, keys, cc, iou_part, max_m, max_i, B, L, C, n, NT);
    }
    k_select<<<(B * n + 3) / 4, 256, 0, stream>>>(
        pred_scores, pred_bboxes, anchor_points, gt_labels, gt_bboxes,
        pad_gt_mask, keys, cc, B, L, C, n, NT);
    k_assign<<<(B * L + 255) / 256, 256, 0, stream>>>(
        pred_scores, pred_bboxes, gt_bboxes, gt_labels, cc, iou_part,
        bg_ptr, assigned_g, align_val, max_m, max_i, out_labels, out_bboxes,
        B, L, C, n);
    if ((C & 3) == 0) {
        int total4 = B * L * (C >> 2);
        k_scores4<<<(total4 + 255) / 256, 256, 0, stream>>>(
            assigned_g, align_val, max_m, max_i, gt_labels, bg_ptr,
            (float4*)out_scores, B, L, C, n, total4);
    } else {
        int total = B * L * C;
        k_scores1<<<(total + 255) / 256, 256, 0, stream>>>(
            assigned_g, align_val, max_m, max_i, gt_labels, bg_ptr,
            out_scores, B, L, C, n, total);
    }
}

// Round 9
// 51.010 us; speedup vs baseline: 1.2851x; 1.2851x over previous
//
#include <hip/hip_runtime.h>
#include <cstdint>

#define NTOPK 13
#define FEPS 1e-9f
#define SLOTS 4         // per-(gt, anchor-tile) key slots (positives/tile ~<=1)
#define KMAX 8          // max key slots per lane in select
#define GSPLIT 4        // gt-dimension split of the scan grid
#define MASKED_FLAG (1 << 30)
#define SENTINEL 0xFFFFFFFFFFFFFFFFull

// ---------------------------------------------------------------------------
// metric[l] for one gt. Identical arithmetic to the reference.
// ---------------------------------------------------------------------------
__device__ __forceinline__ float tal_metric(int l, float4 gb, float ag,
                                            const float4* __restrict__ pb,
                                            const float* __restrict__ ps,
                                            const float2* __restrict__ apt,
                                            int C) {
    float2 a = apt[l];
    float dmin = fminf(fminf(a.x - gb.x, a.y - gb.y),
                       fminf(gb.z - a.x, gb.w - a.y));
    float m = 0.0f;
    if (dmin > FEPS) {
        float4 p = pb[l];
        float iw = fmaxf(fminf(gb.z, p.z) - fmaxf(gb.x, p.x), 0.0f);
        float ih = fmaxf(fminf(gb.w, p.w) - fmaxf(gb.y, p.y), 0.0f);
        float inter = iw * ih;
        float ap2 = (p.z - p.x) * (p.w - p.y);
        float iou = inter / (((ag + ap2) - inter) + 1e-9f);
        m = ps[(size_t)l * C] * powf(iou, 6.0f);
    }
    return m;
}

// ---------------------------------------------------------------------------
// Kernel 1: scan. Block = (anchor tile, batch, gt-slice). Thread owns one
// anchor, loops the slice's gts staged in LDS.
//  - IoU division SKIPPED when inter==0 (iou==0 exactly, matches reference).
//  - per-slice argmax-IoU packed key (iou_bits<<32 | ~g) -> plain store.
//  - positives (metric>0) go into this block's EXCLUSIVE key range
//    keys[bg][tile][0..SLOTS) via LDS counters; unused slots zero-filled,
//    overflow marked SENTINEL (select falls back to dense recompute).
//  - z==0 blocks zero their cc rows; (z==0,tile==0) zero max_m/max_i.
// No global pre-zeroing kernel needed.
// ---------------------------------------------------------------------------
__global__ __launch_bounds__(256) void k_scan(
        const float* __restrict__ pred_scores,
        const float4* __restrict__ pred_bboxes,
        const float2* __restrict__ anchor_points,
        const int* __restrict__ gt_labels,
        const float4* __restrict__ gt_bboxes,
        const float* __restrict__ pad_gt_mask,
        unsigned long long* __restrict__ keys,       // [B*n][NT][SLOTS]
        unsigned long long* __restrict__ cc,         // [B*L] count<<32 | g+1
        unsigned long long* __restrict__ iou_part,   // [GSPLIT][B*L]
        uint32_t* __restrict__ max_m,
        uint32_t* __restrict__ max_i,
        int B, int L, int C, int n, int NT) {
    int b = blockIdx.y;
    int tile = blockIdx.x;
    int l0 = tile * 256;
    int t = threadIdx.x;
    int per = (n + GSPLIT - 1) / GSPLIT;
    int gbeg = min(n, (int)blockIdx.z * per);
    int gend = min(n, gbeg + per);
    int ng = gend - gbeg;

    extern __shared__ char smem[];
    float4* sbox = (float4*)smem;          // RAW gt boxes (argmax uses unmasked)
    int*    slab = (int*)(sbox + per);     // label | MASKED_FLAG
    int*    scnt = slab + per;             // per-gt slot counters

    for (int i = t; i < ng; i += 256) {
        int g = gbeg + i;
        sbox[i] = gt_bboxes[(size_t)b * n + g];
        int lm = gt_labels[(size_t)b * n + g];
        if (pad_gt_mask[(size_t)b * n + g] == 0.0f) lm |= MASKED_FLAG;
        slab[i] = lm;
        scnt[i] = 0;
    }
    if (blockIdx.z == 0) {
        int rows = min(256, L - l0);
        for (int r = t; r < rows; r += 256) cc[(size_t)b * L + l0 + r] = 0ull;
        if (tile == 0)
            for (int i = t; i < n; i += 256) {
                max_m[(size_t)b * n + i] = 0u;
                max_i[(size_t)b * n + i] = 0u;
            }
    }
    __syncthreads();

    int l = l0 + t;
    if (l < L) {
        float2 a = anchor_points[l];
        float4 p = pred_bboxes[(size_t)b * L + l];
        float ap = (p.z - p.x) * (p.w - p.y);
        const float* ps = pred_scores + ((size_t)b * L + l) * C;

        unsigned long long bestkey = 0ull;
        for (int i = 0; i < ng; ++i) {
            float4 gb = sbox[i];
            float iw = fmaxf(fminf(gb.z, p.z) - fmaxf(gb.x, p.x), 0.0f);
            float ih = fmaxf(fminf(gb.w, p.w) - fmaxf(gb.y, p.y), 0.0f);
            float inter = iw * ih;
            int g = gbeg + i;
            unsigned long long akey = (unsigned long long)(uint32_t)(~g);
            int lm = slab[i];
            if (inter > 0.0f) {
                float ag = (gb.z - gb.x) * (gb.w - gb.y);
                float iou = inter / (((ag + ap) - inter) + 1e-9f);
                akey |= (unsigned long long)__float_as_uint(iou) << 32;
                if (!(lm & MASKED_FLAG)) {
                    float dmin = fminf(fminf(a.x - gb.x, a.y - gb.y),
                                       fminf(gb.z - a.x, gb.w - a.y));
                    if (dmin > FEPS) {
                        float m = ps[lm] * powf(iou, 6.0f);
                        if (m > 0.0f) {
                            int slot = atomicAdd(&scnt[i], 1);
                            if (slot < SLOTS)
                                keys[(((size_t)(b * n + g)) * NT + tile) * SLOTS + slot] =
                                    ((unsigned long long)__float_as_uint(m) << 32) |
                                    (uint32_t)(~l);
                        }
                    }
                }
            }
            if (akey > bestkey) bestkey = akey;   // iou desc, then lowest g
        }
        iou_part[(size_t)blockIdx.z * B * L + (size_t)b * L + l] = bestkey;
    }
    __syncthreads();

    // zero unused slots / mark overflow in this block's exclusive key range
    for (int s = t; s < ng * SLOTS; s += 256) {
        int i = s / SLOTS, j = s - i * SLOTS;
        int c = scnt[i];
        unsigned long long* dst =
            &keys[(((size_t)(b * n + gbeg + i)) * NT + tile) * SLOTS + j];
        if (c > SLOTS && j == 0) *dst = SENTINEL;
        else if (j >= c) *dst = 0ull;
    }
}

// ---------------------------------------------------------------------------
// Kernel 2: selection. One wave per (b,g):
//  - load the bg's NT*SLOTS keys (~3 per lane), up-to-13 shfl-max rounds
//    (key desc == value desc then index asc; 0-key = empty sorts last),
//    uniform early break; ballot zero-fill of lowest-index zero-metric
//    anchors; SENTINEL -> dense recompute fallback.
//  - picks: atomicAdd cc[b,l] += (1<<32)|(g+1) iff anchor in-gts.
// ---------------------------------------------------------------------------
__global__ __launch_bounds__(256) void k_select(
        const float* __restrict__ pred_scores,
        const float4* __restrict__ pred_bboxes,
        const float2* __restrict__ anchor_points,
        const int* __restrict__ gt_labels,
        const float4* __restrict__ gt_bboxes,
        const float* __restrict__ pad_gt_mask,
        const unsigned long long* __restrict__ keys,
        unsigned long long* __restrict__ cc,
        int B, int L, int C, int n, int NT) {
    int wid = threadIdx.x >> 6;
    int lane = threadIdx.x & 63;
    int bg = blockIdx.x * 4 + wid;
    if (bg >= B * n) return;
    if (pad_gt_mask[bg] == 0.0f) return;
    int b = bg / n;
    int g = bg - b * n;

    int TK = NT * SLOTS;
    int mypick = -1;
    bool dense = (TK > 64 * KMAX);

    if (!dense) {
        unsigned long long lk[KMAX];
        int nk = 0;
        bool sent = false;
        for (int s = lane; s < TK; s += 64) {
            unsigned long long k = keys[(size_t)bg * TK + s];
            if (k == SENTINEL) sent = true;
            lk[nk++] = k;
        }
        for (int j = nk; j < KMAX; ++j) lk[j] = 0ull;
        dense = (__ballot(sent) != 0ull);

        if (!dense) {
            int np = 0;
            for (int k = 0; k < NTOPK; ++k) {
                unsigned long long mk = 0ull;
                #pragma unroll
                for (int j = 0; j < KMAX; ++j) mk = (lk[j] > mk) ? lk[j] : mk;
                for (int s = 1; s < 64; s <<= 1) {
                    unsigned long long o = __shfl_xor(mk, s);
                    if (o > mk) mk = o;
                }
                if (mk == 0ull) break;      // uniform across wave
                #pragma unroll
                for (int j = 0; j < KMAX; ++j) if (lk[j] == mk) lk[j] = 0ull;
                if (lane == k) mypick = (int)~(uint32_t)mk;
                ++np;
            }
            // zero-fill: lowest-index anchors not among the positive picks
            int fill = np, c = 0;
            while (fill < NTOPK) {
                bool inP = __ballot(lane < np && mypick == c) != 0ull;
                if (!inP) {
                    if (lane == fill) mypick = c;
                    ++fill;
                }
                ++c;
            }
        }
    }

    if (dense) {
        // dense recompute fallback (not taken for this data)
        float4 gb = gt_bboxes[bg];
        float ag = (gb.z - gb.x) * (gb.w - gb.y);
        const float4* pb = pred_bboxes + (size_t)b * L;
        const float*  ps = pred_scores + ((size_t)b * L) * C + gt_labels[bg];
        for (int k = 0; k < NTOPK; ++k) {
            unsigned long long bk = 0ull;
            for (int l = lane; l < L; l += 64) {
                bool taken = false;
                for (int j = 0; j < k; ++j)
                    taken |= (__shfl(mypick, j) == l);
                if (taken) continue;
                float m = tal_metric(l, gb, ag, pb, ps, anchor_points, C);
                unsigned long long key =
                    ((unsigned long long)__float_as_uint(m) << 32) | (uint32_t)(~l);
                if (key > bk) bk = key;
            }
            for (int s = 1; s < 64; s <<= 1) {
                unsigned long long o = __shfl_xor(bk, s);
                if (o > bk) bk = o;
            }
            if (lane == k) mypick = (int)~(uint32_t)bk;
        }
    }

    if (lane < NTOPK && mypick >= 0) {
        int l = mypick;
        float4 gb = gt_bboxes[bg];
        float2 a = anchor_points[l];
        float dmin = fminf(fminf(a.x - gb.x, a.y - gb.y),
                           fminf(gb.z - a.x, gb.w - a.y));
        if (dmin > FEPS) {
            atomicAdd(&cc[(size_t)b * L + l],
                      (1ull << 32) | (unsigned long long)(uint32_t)(g + 1));
        }
    }
}

// ---------------------------------------------------------------------------
// Kernel 3: per (b,l): resolve assignment from the cc word; sum>1 max-reduces
// the GSPLIT argmax slices. Pure streaming.
// ---------------------------------------------------------------------------
__global__ __launch_bounds__(256) void k_assign(
        const float* __restrict__ pred_scores,
        const float4* __restrict__ pred_bboxes,
        const float4* __restrict__ gt_bboxes,
        const int* __restrict__ gt_labels,
        const unsigned long long* __restrict__ cc,
        const unsigned long long* __restrict__ iou_part,
        const int* __restrict__ bg_ptr,
        int* __restrict__ assigned_g,
        float* __restrict__ align_val,
        uint32_t* __restrict__ max_m,
        uint32_t* __restrict__ max_i,
        float* __restrict__ out_labels,
        float4* __restrict__ out_bboxes,
        int B, int L, int C, int n) {
    int idx = blockIdx.x * blockDim.x + threadIdx.x;
    if (idx >= B * L) return;
    int b = idx / L;

    unsigned long long w = cc[idx];
    int count = (int)(w >> 32);
    int g;
    if (count == 0) g = -1;
    else if (count == 1) g = (int)(uint32_t)w - 1;
    else {
        size_t BL = (size_t)B * L;
        unsigned long long bk = iou_part[idx];
        for (int z = 1; z < GSPLIT; ++z) {
            unsigned long long o = iou_part[(size_t)z * BL + idx];
            if (o > bk) bk = o;
        }
        g = (int)~(uint32_t)bk;   // first-max argmax-IoU over all gts
    }
    assigned_g[idx] = g;

    float av = 0.0f;
    if (g >= 0) {
        float4 p = pred_bboxes[idx];
        float ap = (p.z - p.x) * (p.w - p.y);
        float4 gb = gt_bboxes[(size_t)b * n + g];
        float iw = fmaxf(fminf(gb.z, p.z) - fmaxf(gb.x, p.x), 0.0f);
        float ih = fmaxf(fminf(gb.w, p.w) - fmaxf(gb.y, p.y), 0.0f);
        float inter = iw * ih;
        float ag = (gb.z - gb.x) * (gb.w - gb.y);
        float iou = inter / (((ag + ap) - inter) + 1e-9f);
        int label = gt_labels[(size_t)b * n + g];
        float score = pred_scores[(size_t)idx * C + label];
        av = score * powf(iou, 6.0f);
        atomicMax(&max_m[(size_t)b * n + g], __float_as_uint(av));
        atomicMax(&max_i[(size_t)b * n + g], __float_as_uint(iou));
        out_labels[idx] = (float)label;
        out_bboxes[idx] = gb;
    } else {
        out_labels[idx] = (float)(*bg_ptr);
        out_bboxes[idx] = gt_bboxes[(size_t)b * n];  // agi==0 gather, unmasked
    }
    align_val[idx] = av;
}

// ---------------------------------------------------------------------------
// Kernel 4: scores, float4-vectorized (C % 4 == 0 path).
// ---------------------------------------------------------------------------
__global__ __launch_bounds__(256) void k_scores4(
        const int* __restrict__ assigned_g,
        const float* __restrict__ align_val,
        const uint32_t* __restrict__ max_m,
        const uint32_t* __restrict__ max_i,
        const int* __restrict__ gt_labels,
        const int* __restrict__ bg_ptr,
        float4* __restrict__ out_scores,
        int B, int L, int C, int n, int total4) {
    int idx = blockIdx.x * blockDim.x + threadIdx.x;
    if (idx >= total4) return;
    int C4 = C >> 2;
    int c0 = (idx % C4) * 4;
    int bl = idx / C4;
    int g = assigned_g[bl];
    float4 v = make_float4(0.f, 0.f, 0.f, 0.f);
    if (g >= 0) {
        int b = bl / L;
        int label = gt_labels[(size_t)b * n + g];
        int bgi = *bg_ptr;
        float mm = __uint_as_float(max_m[(size_t)b * n + g]);
        float mi = __uint_as_float(max_i[(size_t)b * n + g]);
        float val = align_val[bl] / (mm + FEPS) * mi;
        int cls0 = (c0     < bgi) ? c0     : c0 + 1;
        int cls1 = (c0 + 1 < bgi) ? c0 + 1 : c0 + 2;
        int cls2 = (c0 + 2 < bgi) ? c0 + 2 : c0 + 3;
        int cls3 = (c0 + 3 < bgi) ? c0 + 3 : c0 + 4;
        if (cls0 == label) v.x = val;
        if (cls1 == label) v.y = val;
        if (cls2 == label) v.z = val;
        if (cls3 == label) v.w = val;
    }
    out_scores[idx] = v;
}

__global__ __launch_bounds__(256) void k_scores1(
        const int* __restrict__ assigned_g,
        const float* __restrict__ align_val,
        const uint32_t* __restrict__ max_m,
        const uint32_t* __restrict__ max_i,
        const int* __restrict__ gt_labels,
        const int* __restrict__ bg_ptr,
        float* __restrict__ out_scores,
        int B, int L, int C, int n, int total) {
    int idx = blockIdx.x * blockDim.x + threadIdx.x;
    if (idx >= total) return;
    int c = idx % C;
    int bl = idx / C;
    int g = assigned_g[bl];
    float v = 0.0f;
    if (g >= 0) {
        int b = bl / L;
        int label = gt_labels[(size_t)b * n + g];
        int bgi = *bg_ptr;
        int cls = (c < bgi) ? c : c + 1;
        if (cls == label) {
            float mm = __uint_as_float(max_m[(size_t)b * n + g]);
            float mi = __uint_as_float(max_i[(size_t)b * n + g]);
            v = align_val[bl] / (mm + FEPS) * mi;
        }
    }
    out_scores[idx] = v;
}

// ---------------------------------------------------------------------------
extern "C" void kernel_launch(void* const* d_in, const int* in_sizes, int n_in,
                              void* d_out, int out_size, void* d_ws, size_t ws_size,
                              hipStream_t stream) {
    const float*  pred_scores   = (const float*)d_in[0];
    const float4* pred_bboxes   = (const float4*)d_in[1];
    const float2* anchor_points = (const float2*)d_in[2];
    const int*    gt_labels     = (const int*)d_in[3];
    const float4* gt_bboxes     = (const float4*)d_in[4];
    const float*  pad_gt_mask   = (const float*)d_in[5];
    const int*    bg_ptr        = (const int*)d_in[6];

    const int L = in_sizes[2] / 2;
    const int B = in_sizes[1] / (L * 4);
    const int C = in_sizes[0] / (B * L);
    const int n = in_sizes[3] / B;
    const int NT = (L + 255) / 256;

    char* ws = (char*)d_ws;
    unsigned long long* keys = (unsigned long long*)ws;
    ws += (size_t)B * n * NT * SLOTS * sizeof(unsigned long long);
    unsigned long long* cc = (unsigned long long*)ws;
    ws += (size_t)B * L * sizeof(unsigned long long);
    unsigned long long* iou_part = (unsigned long long*)ws;
    ws += (size_t)GSPLIT * B * L * sizeof(unsigned long long);
    uint32_t* max_m    = (uint32_t*)ws;  ws += (size_t)B * n * sizeof(uint32_t);
    uint32_t* max_i    = (uint32_t*)ws;  ws += (size_t)B * n * sizeof(uint32_t);
    int*      assigned_g = (int*)ws;     ws += (size_t)B * L * sizeof(int);
    float*    align_val  = (float*)ws;   ws += (size_t)B * L * sizeof(float);

    float*  out_labels = (float*)d_out;
    float4* out_bboxes = (float4*)((float*)d_out + (size_t)B * L);
    float*  out_scores = (float*)d_out + (size_t)B * L * 5;

    {
        int per = (n + GSPLIT - 1) / GSPLIT;
        dim3 grid(NT, B, GSPLIT);
        size_t smem = (size_t)per * (sizeof(float4) + 2 * sizeof(int));
        k_scan<<<grid, 256, smem, stream>>>(
            pred_scores, pred_bboxes, anchor_points, gt_labels, gt_bboxes,
            pad_gt_mask, keys, cc, iou_part, max_m, max_i, B, L, C, n, NT);
    }
    k_select<<<(B * n + 3) / 4, 256, 0, stream>>>(
        pred_scores, pred_bboxes, anchor_points, gt_labels, gt_bboxes,
        pad_gt_mask, keys, cc, B, L, C, n, NT);
    k_assign<<<(B * L + 255) / 256, 256, 0, stream>>>(
        pred_scores, pred_bboxes, gt_bboxes, gt_labels, cc, iou_part,
        bg_ptr, assigned_g, align_val, max_m, max_i, out_labels, out_bboxes,
        B, L, C, n);
    if ((C & 3) == 0) {
        int total4 = B * L * (C >> 2);
        k_scores4<<<(total4 + 255) / 256, 256, 0, stream>>>(
            assigned_g, align_val, max_m, max_i, gt_labels, bg_ptr,
            (float4*)out_scores, B, L, C, n, total4);
    } else {
        int total = B * L * C;
        k_scores1<<<(total + 255) / 256, 256, 0, stream>>>(
            assigned_g, align_val, max_m, max_i, gt_labels, bg_ptr,
            out_scores, B, L, C, n, total);
    }
}

// Round 10
// 49.956 us; speedup vs baseline: 1.3122x; 1.0211x over previous
//
#include <hip/hip_runtime.h>
#include <cstdint>

#define NTOPK 13
#define FEPS 1e-9f
#define SLOTS 4         // per-(gt, anchor-tile) key slots (positives/tile ~<=1)
#define KMAX 4          // key slots per lane in select (supports NT*SLOTS<=256)
#define GSPLIT 4        // gt-dimension split of the scan grid
#define MASKED_FLAG (1 << 30)
#define SENTINEL 0xFFFFFFFFFFFFFFFFull

// ---------------------------------------------------------------------------
// metric[l] for one gt. Identical arithmetic to the reference.
// ---------------------------------------------------------------------------
__device__ __forceinline__ float tal_metric(int l, float4 gb, float ag,
                                            const float4* __restrict__ pb,
                                            const float* __restrict__ ps,
                                            const float2* __restrict__ apt,
                                            int C) {
    float2 a = apt[l];
    float dmin = fminf(fminf(a.x - gb.x, a.y - gb.y),
                       fminf(gb.z - a.x, gb.w - a.y));
    float m = 0.0f;
    if (dmin > FEPS) {
        float4 p = pb[l];
        float iw = fmaxf(fminf(gb.z, p.z) - fmaxf(gb.x, p.x), 0.0f);
        float ih = fmaxf(fminf(gb.w, p.w) - fmaxf(gb.y, p.y), 0.0f);
        float inter = iw * ih;
        float ap2 = (p.z - p.x) * (p.w - p.y);
        float iou = inter / (((ag + ap2) - inter) + 1e-9f);
        m = ps[(size_t)l * C] * powf(iou, 6.0f);
    }
    return m;
}

// ---------------------------------------------------------------------------
// Kernel 1: scan. Block = (anchor tile, batch, gt-slice). Thread owns one
// anchor, loops the slice's gts staged in LDS.
//  - IoU division SKIPPED when inter==0 (iou==0 exactly, matches reference).
//  - per-slice argmax-IoU packed key (iou_bits<<32 | ~g) -> plain store.
//  - positives (metric>0) go into this block's EXCLUSIVE key range
//    keys[bg][tile][0..SLOTS) via LDS counters; unused slots zero-filled,
//    overflow marked SENTINEL (select falls back to dense recompute).
//  - z==0 blocks zero their cc rows; (z==0,tile==0) zero max_m/max_i.
// No global pre-zeroing kernel needed.
// ---------------------------------------------------------------------------
__global__ __launch_bounds__(256) void k_scan(
        const float* __restrict__ pred_scores,
        const float4* __restrict__ pred_bboxes,
        const float2* __restrict__ anchor_points,
        const int* __restrict__ gt_labels,
        const float4* __restrict__ gt_bboxes,
        const float* __restrict__ pad_gt_mask,
        unsigned long long* __restrict__ keys,       // [B*n][NT][SLOTS]
        unsigned long long* __restrict__ cc,         // [B*L] count<<32 | g+1
        unsigned long long* __restrict__ iou_part,   // [GSPLIT][B*L]
        uint32_t* __restrict__ max_m,
        uint32_t* __restrict__ max_i,
        int B, int L, int C, int n, int NT) {
    int b = blockIdx.y;
    int tile = blockIdx.x;
    int l0 = tile * 256;
    int t = threadIdx.x;
    int per = (n + GSPLIT - 1) / GSPLIT;
    int gbeg = min(n, (int)blockIdx.z * per);
    int gend = min(n, gbeg + per);
    int ng = gend - gbeg;

    extern __shared__ char smem[];
    float4* sbox = (float4*)smem;          // RAW gt boxes (argmax uses unmasked)
    int*    slab = (int*)(sbox + per);     // label | MASKED_FLAG
    int*    scnt = slab + per;             // per-gt slot counters

    for (int i = t; i < ng; i += 256) {
        int g = gbeg + i;
        sbox[i] = gt_bboxes[(size_t)b * n + g];
        int lm = gt_labels[(size_t)b * n + g];
        if (pad_gt_mask[(size_t)b * n + g] == 0.0f) lm |= MASKED_FLAG;
        slab[i] = lm;
        scnt[i] = 0;
    }
    if (blockIdx.z == 0) {
        int rows = min(256, L - l0);
        for (int r = t; r < rows; r += 256) cc[(size_t)b * L + l0 + r] = 0ull;
        if (tile == 0)
            for (int i = t; i < n; i += 256) {
                max_m[(size_t)b * n + i] = 0u;
                max_i[(size_t)b * n + i] = 0u;
            }
    }
    __syncthreads();

    int l = l0 + t;
    if (l < L) {
        float2 a = anchor_points[l];
        float4 p = pred_bboxes[(size_t)b * L + l];
        float ap = (p.z - p.x) * (p.w - p.y);
        const float* ps = pred_scores + ((size_t)b * L + l) * C;

        unsigned long long bestkey = 0ull;
        for (int i = 0; i < ng; ++i) {
            float4 gb = sbox[i];
            float iw = fmaxf(fminf(gb.z, p.z) - fmaxf(gb.x, p.x), 0.0f);
            float ih = fmaxf(fminf(gb.w, p.w) - fmaxf(gb.y, p.y), 0.0f);
            float inter = iw * ih;
            int g = gbeg + i;
            unsigned long long akey = (unsigned long long)(uint32_t)(~g);
            int lm = slab[i];
            if (inter > 0.0f) {
                float ag = (gb.z - gb.x) * (gb.w - gb.y);
                float iou = inter / (((ag + ap) - inter) + 1e-9f);
                akey |= (unsigned long long)__float_as_uint(iou) << 32;
                if (!(lm & MASKED_FLAG)) {
                    float dmin = fminf(fminf(a.x - gb.x, a.y - gb.y),
                                       fminf(gb.z - a.x, gb.w - a.y));
                    if (dmin > FEPS) {
                        float m = ps[lm] * powf(iou, 6.0f);
                        if (m > 0.0f) {
                            int slot = atomicAdd(&scnt[i], 1);
                            if (slot < SLOTS)
                                keys[(((size_t)(b * n + g)) * NT + tile) * SLOTS + slot] =
                                    ((unsigned long long)__float_as_uint(m) << 32) |
                                    (uint32_t)(~l);
                        }
                    }
                }
            }
            if (akey > bestkey) bestkey = akey;   // iou desc, then lowest g
        }
        iou_part[(size_t)blockIdx.z * B * L + (size_t)b * L + l] = bestkey;
    }
    __syncthreads();

    // zero unused slots / mark overflow in this block's exclusive key range
    for (int s = t; s < ng * SLOTS; s += 256) {
        int i = s / SLOTS, j = s - i * SLOTS;
        int c = scnt[i];
        unsigned long long* dst =
            &keys[(((size_t)(b * n + gbeg + i)) * NT + tile) * SLOTS + j];
        if (c > SLOTS && j == 0) *dst = SENTINEL;
        else if (j >= c) *dst = 0ull;
    }
}

// ---------------------------------------------------------------------------
// Kernel 2: selection. One wave per (b,g):
//  - load the bg's NT*SLOTS keys (~3 per lane), up-to-13 shfl-max rounds
//    (key desc == value desc then index asc; 0-key = empty sorts last),
//    uniform early break; ballot zero-fill of lowest-index zero-metric
//    anchors; SENTINEL -> dense recompute fallback.
//  - picks: atomicAdd cc[b,l] += (1<<32)|(g+1) iff anchor in-gts.
// ---------------------------------------------------------------------------
__global__ __launch_bounds__(256) void k_select(
        const float* __restrict__ pred_scores,
        const float4* __restrict__ pred_bboxes,
        const float2* __restrict__ anchor_points,
        const int* __restrict__ gt_labels,
        const float4* __restrict__ gt_bboxes,
        const float* __restrict__ pad_gt_mask,
        const unsigned long long* __restrict__ keys,
        unsigned long long* __restrict__ cc,
        int B, int L, int C, int n, int NT) {
    int wid = threadIdx.x >> 6;
    int lane = threadIdx.x & 63;
    int bg = blockIdx.x * 4 + wid;
    if (bg >= B * n) return;
    if (pad_gt_mask[bg] == 0.0f) return;
    int b = bg / n;
    int g = bg - b * n;

    int TK = NT * SLOTS;
    int mypick = -1;
    bool dense = (TK > 64 * KMAX);

    if (!dense) {
        unsigned long long lk[KMAX];
        int nk = 0;
        bool sent = false;
        for (int s = lane; s < TK; s += 64) {
            unsigned long long k = keys[(size_t)bg * TK + s];
            if (k == SENTINEL) sent = true;
            lk[nk++] = k;
        }
        for (int j = nk; j < KMAX; ++j) lk[j] = 0ull;
        dense = (__ballot(sent) != 0ull);

        if (!dense) {
            int np = 0;
            for (int k = 0; k < NTOPK; ++k) {
                unsigned long long mk = 0ull;
                #pragma unroll
                for (int j = 0; j < KMAX; ++j) mk = (lk[j] > mk) ? lk[j] : mk;
                for (int s = 1; s < 64; s <<= 1) {
                    unsigned long long o = __shfl_xor(mk, s);
                    if (o > mk) mk = o;
                }
                if (mk == 0ull) break;      // uniform across wave
                #pragma unroll
                for (int j = 0; j < KMAX; ++j) if (lk[j] == mk) lk[j] = 0ull;
                if (lane == k) mypick = (int)~(uint32_t)mk;
                ++np;
            }
            // zero-fill: lowest-index anchors not among the positive picks
            int fill = np, c = 0;
            while (fill < NTOPK) {
                bool inP = __ballot(lane < np && mypick == c) != 0ull;
                if (!inP) {
                    if (lane == fill) mypick = c;
                    ++fill;
                }
                ++c;
            }
        }
    }

    if (dense) {
        // dense recompute fallback (not taken for this data)
        float4 gb = gt_bboxes[bg];
        float ag = (gb.z - gb.x) * (gb.w - gb.y);
        const float4* pb = pred_bboxes + (size_t)b * L;
        const float*  ps = pred_scores + ((size_t)b * L) * C + gt_labels[bg];
        for (int k = 0; k < NTOPK; ++k) {
            unsigned long long bk = 0ull;
            for (int l = lane; l < L; l += 64) {
                bool taken = false;
                for (int j = 0; j < k; ++j)
                    taken |= (__shfl(mypick, j) == l);
                if (taken) continue;
                float m = tal_metric(l, gb, ag, pb, ps, anchor_points, C);
                unsigned long long key =
                    ((unsigned long long)__float_as_uint(m) << 32) | (uint32_t)(~l);
                if (key > bk) bk = key;
            }
            for (int s = 1; s < 64; s <<= 1) {
                unsigned long long o = __shfl_xor(bk, s);
                if (o > bk) bk = o;
            }
            if (lane == k) mypick = (int)~(uint32_t)bk;
        }
    }

    if (lane < NTOPK && mypick >= 0) {
        int l = mypick;
        float4 gb = gt_bboxes[bg];
        float2 a = anchor_points[l];
        float dmin = fminf(fminf(a.x - gb.x, a.y - gb.y),
                           fminf(gb.z - a.x, gb.w - a.y));
        if (dmin > FEPS) {
            atomicAdd(&cc[(size_t)b * L + l],
                      (1ull << 32) | (unsigned long long)(uint32_t)(g + 1));
        }
    }
}

// ---------------------------------------------------------------------------
// Kernel 3: per (b,l): resolve assignment from the cc word; sum>1 max-reduces
// the GSPLIT argmax slices. Writes packed ga = align_bits<<32 | (g+1).
// ---------------------------------------------------------------------------
__global__ __launch_bounds__(256) void k_assign(
        const float* __restrict__ pred_scores,
        const float4* __restrict__ pred_bboxes,
        const float4* __restrict__ gt_bboxes,
        const int* __restrict__ gt_labels,
        const unsigned long long* __restrict__ cc,
        const unsigned long long* __restrict__ iou_part,
        const int* __restrict__ bg_ptr,
        unsigned long long* __restrict__ ga,
        uint32_t* __restrict__ max_m,
        uint32_t* __restrict__ max_i,
        float* __restrict__ out_labels,
        float4* __restrict__ out_bboxes,
        int B, int L, int C, int n) {
    int idx = blockIdx.x * blockDim.x + threadIdx.x;
    if (idx >= B * L) return;
    int b = idx / L;

    unsigned long long w = cc[idx];
    int count = (int)(w >> 32);
    int g;
    if (count == 0) g = -1;
    else if (count == 1) g = (int)(uint32_t)w - 1;
    else {
        size_t BL = (size_t)B * L;
        unsigned long long bk = iou_part[idx];
        for (int z = 1; z < GSPLIT; ++z) {
            unsigned long long o = iou_part[(size_t)z * BL + idx];
            if (o > bk) bk = o;
        }
        g = (int)~(uint32_t)bk;   // first-max argmax-IoU over all gts
    }

    float av = 0.0f;
    if (g >= 0) {
        float4 p = pred_bboxes[idx];
        float ap = (p.z - p.x) * (p.w - p.y);
        float4 gb = gt_bboxes[(size_t)b * n + g];
        float iw = fmaxf(fminf(gb.z, p.z) - fmaxf(gb.x, p.x), 0.0f);
        float ih = fmaxf(fminf(gb.w, p.w) - fmaxf(gb.y, p.y), 0.0f);
        float inter = iw * ih;
        float ag = (gb.z - gb.x) * (gb.w - gb.y);
        float iou = inter / (((ag + ap) - inter) + 1e-9f);
        int label = gt_labels[(size_t)b * n + g];
        float score = pred_scores[(size_t)idx * C + label];
        av = score * powf(iou, 6.0f);
        atomicMax(&max_m[(size_t)b * n + g], __float_as_uint(av));
        atomicMax(&max_i[(size_t)b * n + g], __float_as_uint(iou));
        out_labels[idx] = (float)label;
        out_bboxes[idx] = gb;
    } else {
        out_labels[idx] = (float)(*bg_ptr);
        out_bboxes[idx] = gt_bboxes[(size_t)b * n];  // agi==0 gather, unmasked
    }
    ga[idx] = ((unsigned long long)__float_as_uint(av) << 32) |
              (unsigned long long)(uint32_t)(g + 1);
}

// ---------------------------------------------------------------------------
// Kernel 4: scores, float4-vectorized (C % 4 == 0 path). One 8B ga load
// replaces the former assigned_g + align_val pair.
// ---------------------------------------------------------------------------
__global__ __launch_bounds__(256) void k_scores4(
        const unsigned long long* __restrict__ ga,
        const uint32_t* __restrict__ max_m,
        const uint32_t* __restrict__ max_i,
        const int* __restrict__ gt_labels,
        const int* __restrict__ bg_ptr,
        float4* __restrict__ out_scores,
        int B, int L, int C, int n, int total4) {
    int idx = blockIdx.x * blockDim.x + threadIdx.x;
    if (idx >= total4) return;
    int C4 = C >> 2;
    int c0 = (idx % C4) * 4;
    int bl = idx / C4;
    unsigned long long w = ga[bl];
    int g = (int)(uint32_t)w - 1;
    float4 v = make_float4(0.f, 0.f, 0.f, 0.f);
    if (g >= 0) {
        int b = bl / L;
        int label = gt_labels[(size_t)b * n + g];
        int bgi = *bg_ptr;
        float mm = __uint_as_float(max_m[(size_t)b * n + g]);
        float mi = __uint_as_float(max_i[(size_t)b * n + g]);
        float val = __uint_as_float((uint32_t)(w >> 32)) / (mm + FEPS) * mi;
        int cls0 = (c0     < bgi) ? c0     : c0 + 1;
        int cls1 = (c0 + 1 < bgi) ? c0 + 1 : c0 + 2;
        int cls2 = (c0 + 2 < bgi) ? c0 + 2 : c0 + 3;
        int cls3 = (c0 + 3 < bgi) ? c0 + 3 : c0 + 4;
        if (cls0 == label) v.x = val;
        if (cls1 == label) v.y = val;
        if (cls2 == label) v.z = val;
        if (cls3 == label) v.w = val;
    }
    out_scores[idx] = v;
}

__global__ __launch_bounds__(256) void k_scores1(
        const unsigned long long* __restrict__ ga,
        const uint32_t* __restrict__ max_m,
        const uint32_t* __restrict__ max_i,
        const int* __restrict__ gt_labels,
        const int* __restrict__ bg_ptr,
        float* __restrict__ out_scores,
        int B, int L, int C, int n, int total) {
    int idx = blockIdx.x * blockDim.x + threadIdx.x;
    if (idx >= total) return;
    int c = idx % C;
    int bl = idx / C;
    unsigned long long w = ga[bl];
    int g = (int)(uint32_t)w - 1;
    float v = 0.0f;
    if (g >= 0) {
        int b = bl / L;
        int label = gt_labels[(size_t)b * n + g];
        int bgi = *bg_ptr;
        int cls = (c < bgi) ? c : c + 1;
        if (cls == label) {
            float mm = __uint_as_float(max_m[(size_t)b * n + g]);
            float mi = __uint_as_float(max_i[(size_t)b * n + g]);
            v = __uint_as_float((uint32_t)(w >> 32)) / (mm + FEPS) * mi;
        }
    }
    out_scores[idx] = v;
}

// ---------------------------------------------------------------------------
extern "C" void kernel_launch(void* const* d_in, const int* in_sizes, int n_in,
                              void* d_out, int out_size, void* d_ws, size_t ws_size,
                              hipStream_t stream) {
    const float*  pred_scores   = (const float*)d_in[0];
    const float4* pred_bboxes   = (const float4*)d_in[1];
    const float2* anchor_points = (const float2*)d_in[2];
    const int*    gt_labels     = (const int*)d_in[3];
    const float4* gt_bboxes     = (const float4*)d_in[4];
    const float*  pad_gt_mask   = (const float*)d_in[5];
    const int*    bg_ptr        = (const int*)d_in[6];

    const int L = in_sizes[2] / 2;
    const int B = in_sizes[1] / (L * 4);
    const int C = in_sizes[0] / (B * L);
    const int n = in_sizes[3] / B;
    const int NT = (L + 255) / 256;

    char* ws = (char*)d_ws;
    unsigned long long* keys = (unsigned long long*)ws;
    ws += (size_t)B * n * NT * SLOTS * sizeof(unsigned long long);
    unsigned long long* cc = (unsigned long long*)ws;
    ws += (size_t)B * L * sizeof(unsigned long long);
    unsigned long long* iou_part = (unsigned long long*)ws;
    ws += (size_t)GSPLIT * B * L * sizeof(unsigned long long);
    uint32_t* max_m = (uint32_t*)ws;  ws += (size_t)B * n * sizeof(uint32_t);
    uint32_t* max_i = (uint32_t*)ws;  ws += (size_t)B * n * sizeof(uint32_t);
    unsigned long long* ga = (unsigned long long*)ws;
    ws += (size_t)B * L * sizeof(unsigned long long);

    float*  out_labels = (float*)d_out;
    float4* out_bboxes = (float4*)((float*)d_out + (size_t)B * L);
    float*  out_scores = (float*)d_out + (size_t)B * L * 5;

    {
        int per = (n + GSPLIT - 1) / GSPLIT;
        dim3 grid(NT, B, GSPLIT);
        size_t smem = (size_t)per * (sizeof(float4) + 2 * sizeof(int));
        k_scan<<<grid, 256, smem, stream>>>(
            pred_scores, pred_bboxes, anchor_points, gt_labels, gt_bboxes,
            pad_gt_mask, keys, cc, iou_part, max_m, max_i, B, L, C, n, NT);
    }
    k_select<<<(B * n + 3) / 4, 256, 0, stream>>>(
        pred_scores, pred_bboxes, anchor_points, gt_labels, gt_bboxes,
        pad_gt_mask, keys, cc, B, L, C, n, NT);
    k_assign<<<(B * L + 255) / 256, 256, 0, stream>>>(
        pred_scores, pred_bboxes, gt_bboxes, gt_labels, cc, iou_part,
        bg_ptr, ga, max_m, max_i, out_labels, out_bboxes, B, L, C, n);
    if ((C & 3) == 0) {
        int total4 = B * L * (C >> 2);
        k_scores4<<<(total4 + 255) / 256, 256, 0, stream>>>(
            ga, max_m, max_i, gt_labels, bg_ptr,
            (float4*)out_scores, B, L, C, n, total4);
    } else {
        int total = B * L * C;
        k_scores1<<<(total + 255) / 256, 256, 0, stream>>>(
            ga, max_m, max_i, gt_labels, bg_ptr,
            out_scores, B, L, C, n, total);
    }
}